// Round 5
// baseline (7022.319 us; speedup 1.0000x reference)
//
#include <hip/hip_runtime.h>
#include <stdint.h>

#define Bv 64
#define Tv 2048
#define T1v 1024
#define Dv 128
#define Hv 256

typedef _Float16 h2_t __attribute__((ext_vector_type(2)));

__device__ inline float d2(uint32_t hp, uint32_t wp, float acc) {
#if __has_builtin(__builtin_amdgcn_fdot2)
  return __builtin_amdgcn_fdot2(__builtin_bit_cast(h2_t, hp),
                                __builtin_bit_cast(h2_t, wp), acc, false);
#else
  float out;
  asm("v_dot2_f32_f16 %0, %1, %2, %3" : "=v"(out) : "v"(hp), "v"(wp), "v"(acc));
  return out;
#endif
}

__device__ inline uint16_t f2h(float x) {
  _Float16 h = (_Float16)x;
  return __builtin_bit_cast(uint16_t, h);
}
__device__ inline float h2f(uint16_t u) {
  return (float)__builtin_bit_cast(_Float16, u);
}
__device__ inline uint32_t packpair(float a, float b) {
  return (uint32_t)f2h(a) | ((uint32_t)f2h(b) << 16);
}
__device__ inline float unpk(uint32_t u, int hi) {
  return h2f((uint16_t)(hi ? (u >> 16) : (u & 0xffff)));
}
__device__ inline float sigm(float x) { return 1.f / (1.f + __expf(-x)); }
__device__ inline float tanh_(float x) { return 2.f / (1.f + __expf(-2.f * x)) - 1.f; }

// butterfly sum over the 4 lanes of a quad (VALU DPP, no LDS)
__device__ inline float qsum4(float v) {
  int t = __builtin_amdgcn_update_dpp(0, __float_as_int(v), 0xB1, 0xF, 0xF, true);
  v += __int_as_float(t);
  t = __builtin_amdgcn_update_dpp(0, __float_as_int(v), 0x4E, 0xF, 0xF, true);
  return v + __int_as_float(t);
}

// ---------------- prep kernels ----------------

__global__ void k_pack_x(const float* __restrict__ x, uint32_t* __restrict__ xpk) {
  int idx = blockIdx.x * 256 + threadIdx.x;  // B*T*64
  const float2* x2 = (const float2*)x;
  float2 v = x2[idx];
  xpk[idx] = packpair(v.x, v.y);
}

// OLD layout (fallback kernel k_rnn5): wAll [128][1024] k2-major; wLg [8][1024] uint4;
// wStr [1024][48]
__global__ void k_pack_w(const float* __restrict__ src, uint32_t* __restrict__ wAll,
                         uint32_t* __restrict__ wLg, uint32_t* __restrict__ wStr) {
  int idx = blockIdx.x * 256 + threadIdx.x;  // 1024*128
  int row = idx >> 7, k2 = idx & 127;
  uint32_t pr = packpair(src[row * 256 + 2 * k2], src[row * 256 + 2 * k2 + 1]);
  wAll[k2 * 1024 + row] = pr;
  if (k2 >= 96) {
    int g = (k2 - 96) >> 2, qq = (k2 - 96) & 3;
    wLg[(g * 1024 + row) * 4 + qq] = pr;
  }
  if (k2 >= 48 && k2 < 96) wStr[row * 48 + (k2 - 48)] = pr;
}

// NEW layout (k_rnnU): thread tid = jb*4+q (jb 0..127, q 0..3) owns rows
// r(ri) = gate*256 + jb + 128*u_hi with ri = u_hi*4+gate, pairs k2 in [32q,32q+32).
// kk = k2-32q: kk<24 -> on-chip wOn[(ri*24+kk)*512+tid]; kk>=24 -> LDS image
// wLds[( (ri*2 + (kk-24)/4) *512 + tid)*4 + (kk-24)%4]
__global__ void k_pack_w2(const float* __restrict__ src, uint32_t* __restrict__ wOn,
                          uint32_t* __restrict__ wLds) {
  int idx = blockIdx.x * 256 + threadIdx.x;  // 1024*128
  int r = idx >> 7, k2 = idx & 127;
  uint32_t pr = packpair(src[r * 256 + 2 * k2], src[r * 256 + 2 * k2 + 1]);
  int gate = r >> 8, u = r & 255;
  int u_hi = u >> 7, jb = u & 127;
  int q = k2 >> 5, kk = k2 & 31;
  int tid = jb * 4 + q;
  int ri = u_hi * 4 + gate;
  if (kk < 24) {
    wOn[(ri * 24 + kk) * 512 + tid] = pr;
  } else {
    int p = ri * 2 + ((kk - 24) >> 2);
    int c = (kk - 24) & 3;
    wLds[((size_t)p * 512 + tid) * 4 + c] = pr;
  }
}

// bias packed f16: bpk[jb] = uint4, word wi = (bias[row(2wi)], bias[row(2wi+1)])
__global__ void k_bias_pack(const float* __restrict__ b32, uint32_t* __restrict__ bpk) {
  int jb = threadIdx.x;  // 128
  uint32_t w[4];
#pragma unroll
  for (int wi = 0; wi < 4; ++wi) {
    int ri0 = 2 * wi, ri1 = 2 * wi + 1;
    int row0 = (ri0 & 3) * 256 + jb + 128 * (ri0 >> 2);
    int row1 = (ri1 & 3) * 256 + jb + 128 * (ri1 >> 2);
    w[wi] = packpair(b32[row0], b32[row1]);
  }
  ((uint4*)bpk)[jb] = make_uint4(w[0], w[1], w[2], w[3]);
}

__global__ void k_pack_wih(const float* __restrict__ Wih, uint32_t* __restrict__ wihp) {
  int idx = blockIdx.x * 256 + threadIdx.x;  // 1024*64
  int row = idx >> 6, k2 = idx & 63;
  wihp[row * 64 + k2] = packpair(Wih[row * 128 + 2 * k2], Wih[row * 128 + 2 * k2 + 1]);
}

__global__ void k_bias2(const float* __restrict__ bih, const float* __restrict__ bhh,
                        float* __restrict__ bias) {
  int i = blockIdx.x * 256 + threadIdx.x;
  if (i < 1024) bias[i] = bih[i] + bhh[i];
}

__global__ void k_dec_combine(const float* __restrict__ Whh, const float* __restrict__ Wih,
                              const float* __restrict__ bih, const float* __restrict__ bhh,
                              const float* __restrict__ lW, const float* __restrict__ lb,
                              float* __restrict__ wd, float* __restrict__ bias) {
  int j = blockIdx.x;
  int k = threadIdx.x;
  __shared__ float wr[128];
  if (k < 128) wr[k] = Wih[j * 128 + k];
  __syncthreads();
  float acc = Whh[j * 256 + k];
  for (int d = 0; d < 128; ++d) acc += wr[d] * lW[d * 256 + k];
  wd[j * 256 + k] = acc;
  if (k == 0) {
    float s = bih[j] + bhh[j];
    for (int d = 0; d < 128; ++d) s += wr[d] * lb[d];
    bias[j] = s;
  }
}

__global__ void k_pack_wl(const float* __restrict__ lW, uint32_t* __restrict__ wlp) {
  int idx = blockIdx.x * 256 + threadIdx.x;  // 128*128
  int d = idx >> 7, k2 = idx & 127;
  wlp[d * 128 + k2] = packpair(lW[d * 256 + 2 * k2], lW[d * 256 + 2 * k2 + 1]);
}

// Xp precompute. LAY=0: new layout xp16[((b*1024+s)*128+jb)*8 + ri]
//                LAY=1: old layout xp16[((b*1024+s)*1024 + r]
template <int LAY>
__global__ __launch_bounds__(256) void k_xp_gemm(const uint32_t* __restrict__ xpk,
                                                 const uint32_t* __restrict__ wihp,
                                                 uint16_t* __restrict__ xp, int xt0, int xdt) {
  const int b = blockIdx.z;
  const int s0 = blockIdx.y * 32;
  const int r = blockIdx.x * 256 + threadIdx.x;
  uint32_t wreg[64];
#pragma unroll
  for (int k = 0; k < 64; ++k) wreg[k] = wihp[r * 64 + k];
  const int gate = r >> 8, u = r & 255;
  const int u_hi = u >> 7, jb = u & 127;
  const int ri = u_hi * 4 + gate;
  for (int sl = 0; sl < 32; ++sl) {
    const int s = s0 + sl;
    const int t = xt0 + s * xdt;
    const uint32_t* __restrict__ xrow = xpk + ((size_t)b * Tv + t) * 64;
    float a0 = 0.f, a1 = 0.f;
#pragma unroll
    for (int k = 0; k < 64; k += 2) {
      a0 = d2(xrow[k], wreg[k], a0);
      a1 = d2(xrow[k + 1], wreg[k + 1], a1);
    }
    uint16_t v = f2h(a0 + a1);
    if (LAY == 0)
      xp[(((size_t)b * T1v + s) * 128 + jb) * 8 + ri] = v;
    else
      xp[((size_t)b * T1v + s) * 1024 + r] = v;
  }
}

// ---------------- NEW recurrence kernel (unit-fused, K-split 4) ----------------

struct CfgU {
  const uint32_t* wOn;  // [192][512]
  const uint4* wLds;    // [16][512] uint4
  const uint4* bpk;     // [128] packed f16 bias
  const uint4* xps;     // [B][1024][128] uint4 (8 f16 per jb) or null
  const float* h0;
  const float* c0;
  float* hN;
  float* cN;
  uint16_t* hist;  // [B][1024][256] or null
};

__global__ void __launch_bounds__(512)
__attribute__((amdgpu_waves_per_eu(2, 2)))
k_rnnU(CfgU cA, CfgU cB, int nA) {
  __shared__ __align__(16) uint4 wldsM[16 * 512];  // 128 KB
  __shared__ __align__(16) uint16_t hb[2][256];    // h double buffer

  const bool isA = (int)blockIdx.x < nA;
  const CfgU cfg = isA ? cA : cB;
  const int b = isA ? (int)blockIdx.x : ((int)blockIdx.x - nA);
  const int tid = threadIdx.x;
  const int q = tid & 3, jb = tid >> 2;
  const float qz = (q == 0) ? 1.f : 0.f;

#pragma unroll
  for (int i = 0; i < 16; ++i) wldsM[i * 512 + tid] = cfg.wLds[i * 512 + tid];

  uint32_t wreg[192];
#pragma unroll
  for (int k = 0; k < 192; ++k) wreg[k] = cfg.wOn[k * 512 + tid];

  const uint4 bp = cfg.bpk[jb];
  float c0r = cfg.c0 ? cfg.c0[b * 256 + jb] : 0.f;
  float c1r = cfg.c0 ? cfg.c0[b * 256 + jb + 128] : 0.f;

  uint16_t* histp = cfg.hist ? cfg.hist + (size_t)b * 1024 * 256 : nullptr;
  if (q == 0) {
    float h00 = cfg.h0 ? cfg.h0[b * 256 + jb] : 0.f;
    float h01 = cfg.h0 ? cfg.h0[b * 256 + jb + 128] : 0.f;
    uint16_t u0 = f2h(h00), u1 = f2h(h01);
    hb[0][jb] = u0;
    hb[0][jb + 128] = u1;
    if (histp) {
      histp[jb] = u0;
      histp[jb + 128] = u1;
    }
  }
  const uint4* xps4 = cfg.xps ? cfg.xps + (size_t)b * 1024 * 128 + jb : nullptr;

  __syncthreads();

  int cur = 0;
  for (int s = 0; s < 1024; ++s) {
    uint4 xq = make_uint4(0, 0, 0, 0);
    if (xps4) xq = xps4[(size_t)s * 128];

    float acc[8];
    acc[0] = qz * (unpk(bp.x, 0) + unpk(xq.x, 0));
    acc[1] = qz * (unpk(bp.x, 1) + unpk(xq.x, 1));
    acc[2] = qz * (unpk(bp.y, 0) + unpk(xq.y, 0));
    acc[3] = qz * (unpk(bp.y, 1) + unpk(xq.y, 1));
    acc[4] = qz * (unpk(bp.z, 0) + unpk(xq.z, 0));
    acc[5] = qz * (unpk(bp.z, 1) + unpk(xq.z, 1));
    acc[6] = qz * (unpk(bp.w, 0) + unpk(xq.w, 0));
    acc[7] = qz * (unpk(bp.w, 1) + unpk(xq.w, 1));

    const uint4* H4 = (const uint4*)hb[cur];
#pragma unroll
    for (int c = 0; c < 6; ++c) {  // on-chip weight pairs (24 per row)
      const uint4 hv = H4[q * 8 + c];
#pragma unroll
      for (int ri = 0; ri < 8; ++ri) {
        const int base = ri * 24 + c * 4;
        acc[ri] = d2(hv.x, wreg[base + 0], acc[ri]);
        acc[ri] = d2(hv.y, wreg[base + 1], acc[ri]);
        acc[ri] = d2(hv.z, wreg[base + 2], acc[ri]);
        acc[ri] = d2(hv.w, wreg[base + 3], acc[ri]);
      }
    }
#pragma unroll
    for (int p = 0; p < 2; ++p) {  // LDS weight pairs (8 per row)
      const uint4 hv = H4[q * 8 + 6 + p];
#pragma unroll
      for (int ri = 0; ri < 8; ++ri) {
        const uint4 wv = wldsM[(ri * 2 + p) * 512 + tid];
        acc[ri] = d2(hv.x, wv.x, acc[ri]);
        acc[ri] = d2(hv.y, wv.y, acc[ri]);
        acc[ri] = d2(hv.z, wv.z, acc[ri]);
        acc[ri] = d2(hv.w, wv.w, acc[ri]);
      }
    }

#pragma unroll
    for (int ri = 0; ri < 8; ++ri) acc[ri] = qsum4(acc[ri]);

    // unit 0 (rows jb): i,f,g,o = acc[0..3]
    const float cn0 = sigm(acc[1]) * c0r + sigm(acc[0]) * tanh_(acc[2]);
    const float h0v = sigm(acc[3]) * tanh_(cn0);
    c0r = cn0;
    // unit 1 (rows jb+128): acc[4..7]
    const float cn1 = sigm(acc[5]) * c1r + sigm(acc[4]) * tanh_(acc[6]);
    const float h1v = sigm(acc[7]) * tanh_(cn1);
    c1r = cn1;

    const uint16_t hu0 = f2h(h0v), hu1 = f2h(h1v);
    if (q == 0) {
      hb[cur ^ 1][jb] = hu0;
      hb[cur ^ 1][jb + 128] = hu1;
      if (histp && s < 1023) {
        histp[(size_t)(s + 1) * 256 + jb] = hu0;
        histp[(size_t)(s + 1) * 256 + jb + 128] = hu1;
      }
    }
    __syncthreads();
    cur ^= 1;
  }

  if (cfg.hN && q == 0) {
    cfg.hN[b * 256 + jb] = h2f(hb[cur][jb]);
    cfg.hN[b * 256 + jb + 128] = h2f(hb[cur][jb + 128]);
    cfg.cN[b * 256 + jb] = c0r;
    cfg.cN[b * 256 + jb + 128] = c1r;
  }
}

// ---------------- OLD recurrence kernel (R4-proven fallback) ----------------

struct ChainCfg {
  const uint32_t* wAll;
  const uint4* wLg;
  const uint32_t* wStr;
  const uint32_t* wih;
  const uint32_t* xpk;
  const uint16_t* xps;  // old layout [B][1024][1024]
  const float* bias;
  const float* h0;
  const float* c0;
  float* hN;
  float* cN;
  uint16_t* hist;
  int xt0, xdt;
};

template <int NRESP, bool WIH>
__global__ void __launch_bounds__(512)
__attribute__((amdgpu_waves_per_eu(2, 2)))
k_rnn5(ChainCfg cA, ChainCfg cB, int nA) {
  __shared__ __align__(16) uint4 wlds4[8 * 1024];
  __shared__ float gsm[1024];
  __shared__ __align__(16) uint16_t h16[256];
  __shared__ __align__(16) uint32_t xsh[64];

  const bool isA = (int)blockIdx.x < nA;
  const ChainCfg cfg = isA ? cA : cB;
  const int b = isA ? (int)blockIdx.x : ((int)blockIdx.x - nA);
  const int tid = threadIdx.x;
  const int r0 = tid, r1 = tid + 512;

#pragma unroll
  for (int i = 0; i < 16; ++i) wlds4[i * 512 + tid] = cfg.wLg[i * 512 + tid];

  uint16_t* histp = cfg.hist ? cfg.hist + (size_t)b * 1024 * 256 : nullptr;

  float creg = 0.f;
  if (tid < 256) {
    float h0v = cfg.h0 ? cfg.h0[b * 256 + tid] : 0.f;
    creg = cfg.c0 ? cfg.c0[b * 256 + tid] : 0.f;
    uint16_t hu = f2h(h0v);
    h16[tid] = hu;
    if (histp) histp[tid] = hu;
  }

  uint32_t w0[NRESP], w1[NRESP];
#pragma unroll
  for (int k = 0; k < NRESP; ++k) w0[k] = cfg.wAll[k * 1024 + r0];
#pragma unroll
  for (int k = 0; k < NRESP; ++k) w1[k] = cfg.wAll[k * 1024 + r1];
  const float bias0 = cfg.bias[r0];
  const float bias1 = cfg.bias[r1];

  constexpr int NS4 = (96 - NRESP) / 4;
  const uint4* ws0 = (const uint4*)(cfg.wStr + (size_t)r0 * 48 + (NRESP - 48));
  const uint4* ws1 = (const uint4*)(cfg.wStr + (size_t)r1 * 48 + (NRESP - 48));
  const uint4* wi0 = cfg.wih ? (const uint4*)(cfg.wih + (size_t)r0 * 64) : nullptr;
  const uint4* wi1 = cfg.wih ? (const uint4*)(cfg.wih + (size_t)r1 * 64) : nullptr;
  const bool hasx = cfg.xps != nullptr;

  __syncthreads();

  for (int s = 0; s < 1024; ++s) {
    float xa0 = 0.f, xa1 = 0.f;
    if (hasx) {
      size_t xb = ((size_t)b * 1024 + s) * 1024;
      xa0 = h2f(cfg.xps[xb + r0]);
      xa1 = h2f(cfg.xps[xb + r1]);
    }
    if constexpr (WIH) {
      if (cfg.wih) {
        if (tid < 64) {
          const int t = cfg.xt0 + s * cfg.xdt;
          xsh[tid] = cfg.xpk[((size_t)b * Tv + t) * 64 + tid];
        }
        __syncthreads();
      }
    }

    const uint4* H4 = (const uint4*)h16;
    float a00 = bias0, a01 = 0.f, a10 = bias1, a11 = 0.f;

#pragma unroll
    for (int c4 = 0; c4 < NRESP / 4; ++c4) {
      const uint4 hv = H4[c4];
      a00 = d2(hv.x, w0[4 * c4 + 0], a00);
      a01 = d2(hv.y, w0[4 * c4 + 1], a01);
      a10 = d2(hv.x, w1[4 * c4 + 0], a10);
      a11 = d2(hv.y, w1[4 * c4 + 1], a11);
      a00 = d2(hv.z, w0[4 * c4 + 2], a00);
      a01 = d2(hv.w, w0[4 * c4 + 3], a01);
      a10 = d2(hv.z, w1[4 * c4 + 2], a10);
      a11 = d2(hv.w, w1[4 * c4 + 3], a11);
    }
    if constexpr (NS4 > 0) {
#pragma unroll
      for (int u = 0; u < NS4; ++u) {
        const uint4 hv = H4[NRESP / 4 + u];
        const uint4 wv0 = ws0[u];
        const uint4 wv1 = ws1[u];
        a00 = d2(hv.x, wv0.x, a00);
        a01 = d2(hv.y, wv0.y, a01);
        a10 = d2(hv.x, wv1.x, a10);
        a11 = d2(hv.y, wv1.y, a11);
        a00 = d2(hv.z, wv0.z, a00);
        a01 = d2(hv.w, wv0.w, a01);
        a10 = d2(hv.z, wv1.z, a10);
        a11 = d2(hv.w, wv1.w, a11);
      }
    }
#pragma unroll
    for (int g = 0; g < 8; ++g) {
      const uint4 hv = H4[24 + g];
      const uint4 wv0 = wlds4[g * 1024 + r0];
      const uint4 wv1 = wlds4[g * 1024 + r1];
      a00 = d2(hv.x, wv0.x, a00);
      a01 = d2(hv.y, wv0.y, a01);
      a10 = d2(hv.x, wv1.x, a10);
      a11 = d2(hv.y, wv1.y, a11);
      a00 = d2(hv.z, wv0.z, a00);
      a01 = d2(hv.w, wv0.w, a01);
      a10 = d2(hv.z, wv1.z, a10);
      a11 = d2(hv.w, wv1.w, a11);
    }
    if constexpr (WIH) {
      if (cfg.wih) {
        const uint4* XS4 = (const uint4*)xsh;
#pragma unroll
        for (int u = 0; u < 16; ++u) {
          const uint4 xv = XS4[u];
          const uint4 wv0 = wi0[u];
          const uint4 wv1 = wi1[u];
          a00 = d2(xv.x, wv0.x, a00);
          a01 = d2(xv.y, wv0.y, a01);
          a10 = d2(xv.x, wv1.x, a10);
          a11 = d2(xv.y, wv1.y, a11);
          a00 = d2(xv.z, wv0.z, a00);
          a01 = d2(xv.w, wv0.w, a01);
          a10 = d2(xv.z, wv1.z, a10);
          a11 = d2(xv.w, wv1.w, a11);
        }
      }
    }

    gsm[r0] = a00 + a01 + xa0;
    gsm[r1] = a10 + a11 + xa1;
    __syncthreads();

    if (tid < 256) {
      const float gi = gsm[tid];
      const float gf = gsm[tid + 256];
      const float gg = gsm[tid + 512];
      const float go = gsm[tid + 768];
      const float cn = sigm(gf) * creg + sigm(gi) * tanh_(gg);
      const float hv = sigm(go) * tanh_(cn);
      creg = cn;
      const uint16_t hu = f2h(hv);
      h16[tid] = hu;
      if (histp && s < 1023) histp[(size_t)(s + 1) * 256 + tid] = hu;
    }
    __syncthreads();
  }

  if (cfg.hN && tid < 256) {
    cfg.hN[b * 256 + tid] = h2f(h16[tid]);
    cfg.cN[b * 256 + tid] = creg;
  }
}

// ---------------- output GEMM ----------------
__global__ __launch_bounds__(256) void k_out(const uint16_t* __restrict__ hist,
                                             const uint32_t* __restrict__ wlp,
                                             const float* __restrict__ lb,
                                             float* __restrict__ out, int outbase, int tsign) {
  const int b = blockIdx.y;
  const int t0 = blockIdx.x * 64;
  __shared__ __align__(16) uint32_t hq[64 * 128];
  const uint32_t* hsrc = (const uint32_t*)hist;
  for (int i = threadIdx.x; i < 64 * 128; i += 256) {
    hq[i] = hsrc[((size_t)b * 1024 + t0) * 128 + i];
  }
  __syncthreads();
  const int d = threadIdx.x & 127;
  const int th = threadIdx.x >> 7;
  float acc[32];
#pragma unroll
  for (int it = 0; it < 32; ++it) acc[it] = lb[d];
  const uint4* W4 = (const uint4*)(wlp + (size_t)d * 128);
  const uint4* HQ4 = (const uint4*)hq;
  for (int k2c = 0; k2c < 32; ++k2c) {
    const uint4 wv = W4[k2c];
#pragma unroll
    for (int it = 0; it < 32; ++it) {
      const int tl = th * 32 + it;
      const uint4 hv = HQ4[tl * 32 + k2c];
      acc[it] = d2(hv.x, wv.x, acc[it]);
      acc[it] = d2(hv.y, wv.y, acc[it]);
      acc[it] = d2(hv.z, wv.z, acc[it]);
      acc[it] = d2(hv.w, wv.w, acc[it]);
    }
  }
#pragma unroll
  for (int it = 0; it < 32; ++it) {
    const int tl = th * 32 + it;
    const int t = t0 + tl;
    const int tout = outbase + tsign * t;
    out[((size_t)b * Tv + tout) * Dv + d] = acc[it];
  }
}

// ---------------- host ----------------

extern "C" void kernel_launch(void* const* d_in, const int* in_sizes, int n_in,
                              void* d_out, int out_size, void* d_ws, size_t ws_size,
                              hipStream_t stream) {
  const float* x = (const float*)d_in[0];
  const float* e1_Wih = (const float*)d_in[1];
  const float* e1_Whh = (const float*)d_in[2];
  const float* e1_bih = (const float*)d_in[3];
  const float* e1_bhh = (const float*)d_in[4];
  const float* e2_Wih = (const float*)d_in[5];
  const float* e2_Whh = (const float*)d_in[6];
  const float* e2_bih = (const float*)d_in[7];
  const float* e2_bhh = (const float*)d_in[8];
  const float* d1_Wih = (const float*)d_in[9];
  const float* d1_Whh = (const float*)d_in[10];
  const float* d1_bih = (const float*)d_in[11];
  const float* d1_bhh = (const float*)d_in[12];
  const float* d2_Wih = (const float*)d_in[13];
  const float* d2_Whh = (const float*)d_in[14];
  const float* d2_bih = (const float*)d_in[15];
  const float* d2_bhh = (const float*)d_in[16];
  const float* l1_W = (const float*)d_in[17];
  const float* l1_b = (const float*)d_in[18];
  const float* l2_W = (const float*)d_in[19];
  const float* l2_b = (const float*)d_in[20];

  uint8_t* wsb = (uint8_t*)d_ws;
  size_t off = 0;
  auto take = [&](size_t n) -> void* {
    void* pp = wsb + off;
    off += (n + 255) & ~(size_t)255;
    return pp;
  };
  uint32_t* xpk = (uint32_t*)take((size_t)Bv * Tv * 64 * 4);
  uint16_t* hist1 = (uint16_t*)take((size_t)Bv * T1v * Hv * 2);
  uint16_t* hist2 = (uint16_t*)take((size_t)Bv * T1v * Hv * 2);
  struct WSet {
    uint32_t *wAll, *wLg, *wStr, *wih;
    float* bias;
    uint32_t *wOn, *wLds, *bpk;
  };
  auto take_wset = [&](bool with_ih) -> WSet {
    WSet w;
    w.wAll = (uint32_t*)take(128 * 1024 * 4);
    w.wLg = (uint32_t*)take(8 * 1024 * 16);
    w.wStr = (uint32_t*)take(1024 * 48 * 4);
    w.wih = with_ih ? (uint32_t*)take(1024 * 64 * 4) : nullptr;
    w.bias = (float*)take(1024 * 4);
    w.wOn = (uint32_t*)take(192 * 512 * 4);
    w.wLds = (uint32_t*)take(16 * 512 * 16);
    w.bpk = (uint32_t*)take(128 * 16);
    return w;
  };
  WSet we1 = take_wset(true);
  WSet we2 = take_wset(true);
  WSet wd1 = take_wset(false);
  WSet wd2 = take_wset(false);
  float* wd32 = (float*)take(1024 * 256 * 4);
  uint32_t* wl1p = (uint32_t*)take(128 * 128 * 4);
  uint32_t* wl2p = (uint32_t*)take(128 * 128 * 4);
  float* h1 = (float*)take(64 * 256 * 4);
  float* c1 = (float*)take(64 * 256 * 4);
  float* h2 = (float*)take(64 * 256 * 4);
  float* c2 = (float*)take(64 * 256 * 4);
  uint16_t* xp = (uint16_t*)take((size_t)Bv * T1v * 1024 * 2);  // shared e1/e2
  const bool use_xp = ws_size >= off;

  // ---- pick variant ----
  // 0 = new k_rnnU; 1 = old k_rnn5<96>; 2 = old k_rnn5<80>
  int variant = 2;
  {
    hipFuncAttributes fa;
    auto spillfree = [&](const void* f) {
      return hipFuncGetAttributes(&fa, f) == hipSuccess && fa.localSizeBytes == 0;
    };
    if (use_xp && spillfree(reinterpret_cast<const void*>(&k_rnnU))) {
      variant = 0;
    } else if (use_xp) {
      if (spillfree(reinterpret_cast<const void*>(&k_rnn5<96, false>))) variant = 1;
    } else {
      if (spillfree(reinterpret_cast<const void*>(&k_rnn5<96, true>))) variant = 1;
    }
  }

  // ---- prep ----
  k_pack_x<<<(Bv * Tv * 64) / 256, 256, 0, stream>>>(x, xpk);
  // encoder weight packs
  k_pack_w<<<512, 256, 0, stream>>>(e1_Whh, we1.wAll, we1.wLg, we1.wStr);
  k_pack_w2<<<512, 256, 0, stream>>>(e1_Whh, we1.wOn, we1.wLds);
  k_pack_wih<<<256, 256, 0, stream>>>(e1_Wih, we1.wih);
  k_bias2<<<4, 256, 0, stream>>>(e1_bih, e1_bhh, we1.bias);
  k_bias_pack<<<1, 128, 0, stream>>>(we1.bias, we1.bpk);
  k_pack_w<<<512, 256, 0, stream>>>(e2_Whh, we2.wAll, we2.wLg, we2.wStr);
  k_pack_w2<<<512, 256, 0, stream>>>(e2_Whh, we2.wOn, we2.wLds);
  k_pack_wih<<<256, 256, 0, stream>>>(e2_Wih, we2.wih);
  k_bias2<<<4, 256, 0, stream>>>(e2_bih, e2_bhh, we2.bias);
  k_bias_pack<<<1, 128, 0, stream>>>(we2.bias, we2.bpk);
  // decoder combined weights
  k_dec_combine<<<1024, 256, 0, stream>>>(d1_Whh, d1_Wih, d1_bih, d1_bhh, l1_W, l1_b, wd32, wd1.bias);
  k_pack_w<<<512, 256, 0, stream>>>(wd32, wd1.wAll, wd1.wLg, wd1.wStr);
  k_pack_w2<<<512, 256, 0, stream>>>(wd32, wd1.wOn, wd1.wLds);
  k_bias_pack<<<1, 128, 0, stream>>>(wd1.bias, wd1.bpk);
  k_dec_combine<<<1024, 256, 0, stream>>>(d2_Whh, d2_Wih, d2_bih, d2_bhh, l2_W, l2_b, wd32, wd2.bias);
  k_pack_w<<<512, 256, 0, stream>>>(wd32, wd2.wAll, wd2.wLg, wd2.wStr);
  k_pack_w2<<<512, 256, 0, stream>>>(wd32, wd2.wOn, wd2.wLds);
  k_bias_pack<<<1, 128, 0, stream>>>(wd2.bias, wd2.bpk);
  k_pack_wl<<<64, 256, 0, stream>>>(l1_W, wl1p);
  k_pack_wl<<<64, 256, 0, stream>>>(l2_W, wl2p);

  auto launch_old = [&](int grid, ChainCfg a, ChainCfg b2, int nA) {
    if (use_xp) {
      if (variant == 1) k_rnn5<96, false><<<grid, 512, 0, stream>>>(a, b2, nA);
      else              k_rnn5<80, false><<<grid, 512, 0, stream>>>(a, b2, nA);
    } else {
      if (variant == 1) k_rnn5<96, true><<<grid, 512, 0, stream>>>(a, b2, nA);
      else              k_rnn5<80, true><<<grid, 512, 0, stream>>>(a, b2, nA);
    }
  };

  if (variant == 0) {
    // ---- NEW path ----
    k_xp_gemm<0><<<dim3(4, 32, 64), 256, 0, stream>>>(xpk, we1.wih, xp, 1023, -1);
    CfgU e1c{we1.wOn, (const uint4*)we1.wLds, (const uint4*)we1.bpk, (const uint4*)xp,
             nullptr, nullptr, h1, c1, nullptr};
    k_rnnU<<<64, 512, 0, stream>>>(e1c, e1c, 64);

    k_xp_gemm<0><<<dim3(4, 32, 64), 256, 0, stream>>>(xpk, we2.wih, xp, 1024, 1);
    CfgU e2c{we2.wOn, (const uint4*)we2.wLds, (const uint4*)we2.bpk, (const uint4*)xp,
             h1, c1, h2, c2, nullptr};
    CfgU d1c{wd1.wOn, (const uint4*)wd1.wLds, (const uint4*)wd1.bpk, nullptr,
             h1, c1, nullptr, nullptr, hist1};
    k_rnnU<<<128, 512, 0, stream>>>(e2c, d1c, 64);

    CfgU d2c{wd2.wOn, (const uint4*)wd2.wLds, (const uint4*)wd2.bpk, nullptr,
             h2, c2, nullptr, nullptr, hist2};
    k_rnnU<<<64, 512, 0, stream>>>(d2c, d2c, 64);
  } else {
    // ---- OLD (R4-proven) path ----
    if (use_xp) k_xp_gemm<1><<<dim3(4, 32, 64), 256, 0, stream>>>(xpk, we1.wih, xp, 1023, -1);
    ChainCfg e1c{we1.wAll, (const uint4*)we1.wLg, we1.wStr, use_xp ? nullptr : we1.wih,
                 use_xp ? nullptr : xpk, use_xp ? xp : nullptr, we1.bias,
                 nullptr, nullptr, h1, c1, nullptr, 1023, -1};
    launch_old(64, e1c, e1c, 64);

    if (use_xp) k_xp_gemm<1><<<dim3(4, 32, 64), 256, 0, stream>>>(xpk, we2.wih, xp, 1024, 1);
    ChainCfg e2c{we2.wAll, (const uint4*)we2.wLg, we2.wStr, use_xp ? nullptr : we2.wih,
                 use_xp ? nullptr : xpk, use_xp ? xp : nullptr, we2.bias,
                 h1, c1, h2, c2, nullptr, 1024, 1};
    ChainCfg d1c{wd1.wAll, (const uint4*)wd1.wLg, wd1.wStr, nullptr, nullptr, nullptr,
                 wd1.bias, h1, c1, nullptr, nullptr, hist1, 0, 0};
    launch_old(128, e2c, d1c, 64);

    ChainCfg d2c{wd2.wAll, (const uint4*)wd2.wLg, wd2.wStr, nullptr, nullptr, nullptr,
                 wd2.bias, h2, c2, nullptr, nullptr, hist2, 0, 0};
    launch_old(64, d2c, d2c, 64);
  }

  // ---- outputs ----
  k_out<<<dim3(16, 64), 256, 0, stream>>>(hist1, wl1p, l1_b, (float*)d_out, 0, 1);
  k_out<<<dim3(16, 64), 256, 0, stream>>>(hist2, wl2p, l2_b, (float*)d_out, 2047, -1);
}